// Round 1
// baseline (1672.414 us; speedup 1.0000x reference)
//
#include <hip/hip_runtime.h>
#include <math.h>

typedef __bf16 bf16;
typedef __bf16 bf16x8 __attribute__((ext_vector_type(8)));
typedef float floatx4 __attribute__((ext_vector_type(4)));

#define S_LEN 2048
#define BATCH 32
#define NHEAD 8
#define NC_K 19
#define NM_K 10

// ---------------- fp32 -> bf16 flat convert ----------------
__global__ __launch_bounds__(256) void cvt_bf16_kernel(const float* __restrict__ src,
                                                       bf16* __restrict__ dst, long n)
{
    long i = ((long)blockIdx.x * 256 + threadIdx.x) * 8;
    if (i + 8 > n) return;
    float4 a = *(const float4*)(src + i);
    float4 b = *(const float4*)(src + i + 4);
    bf16x8 o;
    o[0]=(bf16)a.x; o[1]=(bf16)a.y; o[2]=(bf16)a.z; o[3]=(bf16)a.w;
    o[4]=(bf16)b.x; o[5]=(bf16)b.y; o[6]=(bf16)b.z; o[7]=(bf16)b.w;
    *(bf16x8*)(dst + i) = o;
}

// ---------------- transpose fp32 [R][Cn] -> bf16 [Cn][R] ----------------
__global__ __launch_bounds__(256) void transpose_to_bf16(const float* __restrict__ src,
                                                         bf16* __restrict__ dst, int R, int Cn)
{
    __shared__ float tile[32][33];
    int tx = threadIdx.x & 31, ty = threadIdx.x >> 5;
    int c0 = blockIdx.x * 32, r0 = blockIdx.y * 32;
    #pragma unroll
    for (int r = ty; r < 32; r += 8)
        tile[r][tx] = src[(size_t)(r0 + r) * Cn + c0 + tx];
    __syncthreads();
    #pragma unroll
    for (int r = ty; r < 32; r += 8)
        dst[(size_t)(c0 + r) * R + r0 + tx] = (bf16)tile[tx][r];
}

// ---------------- P[b] = sum_s em*post ; zero A accumulators ----------------
__global__ __launch_bounds__(256) void init_small(const int* __restrict__ em,
                                                  const int* __restrict__ pmask,
                                                  float* __restrict__ P,
                                                  float* __restrict__ Ac,
                                                  float* __restrict__ Am)
{
    __shared__ int red[256];
    int b = blockIdx.x, tid = threadIdx.x;
    int s = 0;
    for (int i = tid; i < S_LEN; i += 256) s += em[b*S_LEN + i] * pmask[b*S_LEN + i];
    red[tid] = s; __syncthreads();
    for (int off = 128; off; off >>= 1) { if (tid < off) red[tid] += red[tid+off]; __syncthreads(); }
    if (tid == 0) P[b] = (float)red[0];
    for (int i = tid; i < NHEAD*NC_K; i += 256) Ac[b*NHEAD*NC_K + i] = 0.f;
    for (int i = tid; i < NHEAD*NM_K; i += 256) Am[b*NHEAD*NM_K + i] = 0.f;
}

// ---------------- k/v projections for a table (rows blocks) ----------------
__global__ __launch_bounds__(256) void kv_proj(const float* __restrict__ T,
                                               const float* __restrict__ Wk, const float* __restrict__ bk,
                                               const float* __restrict__ Wv, const float* __restrict__ bv,
                                               bf16* __restrict__ kout, bf16* __restrict__ vout,
                                               float* __restrict__ vout32)
{
    __shared__ float trow[512];
    int r = blockIdx.x, tid = threadIdx.x;
    for (int i = tid; i < 512; i += 256) trow[i] = T[r*512 + i];
    __syncthreads();
    for (int j = tid; j < 512; j += 256) {
        float sk = bk[j], sv = bv[j];
        for (int d = 0; d < 512; d++) {
            float t = trow[d];
            sk += t * Wk[d*512 + j];
            sv += t * Wv[d*512 + j];
        }
        kout[r*512 + j] = (bf16)sk;
        vout[r*512 + j] = (bf16)sv;
        vout32[r*512 + j] = sv;
    }
}

// ---------------- WoqT[j][i] = (Wo@Wq)[i][j], bf16 ----------------
__global__ __launch_bounds__(256) void fold_wq(const float* __restrict__ Wo,
                                               const float* __restrict__ Wq,
                                               bf16* __restrict__ WoqT)
{
    __shared__ float worow[512];
    int i = blockIdx.x, tid = threadIdx.x;
    for (int d = tid; d < 512; d += 256) worow[d] = Wo[i*512 + d];
    __syncthreads();
    for (int j = tid; j < 512; j += 256) {
        float s = 0.f;
        for (int d = 0; d < 512; d++) s += worow[d] * Wq[d*512 + j];
        WoqT[(size_t)j*512 + i] = (bf16)s;
    }
}

// ---------------- bq2 = bo@Wq + bq ----------------
__global__ __launch_bounds__(256) void bias_fold(const float* __restrict__ bo,
                                                 const float* __restrict__ Wq,
                                                 const float* __restrict__ bq,
                                                 float* __restrict__ bq2)
{
    int tid = threadIdx.x;
    for (int j = tid; j < 512; j += 256) {
        float s = bq[j];
        for (int d = 0; d < 512; d++) s += bo[d] * Wq[d*512 + j];
        bq2[j] = s;
    }
}

// ---------------- bf16 MFMA GEMM: C[M,N] = A[M,K] @ Wt[N,K]^T + bias ----------------
// 128x128 tile, BK=32, 4 waves, each wave 64x64 via 4x4 mfma_f32_16x16x32_bf16
__global__ __launch_bounds__(256) void gemm_bf16(const bf16* __restrict__ A,
                                                 const bf16* __restrict__ Wt,
                                                 const float* __restrict__ bias,
                                                 bf16* __restrict__ C,
                                                 int M, int N, int K)
{
    __shared__ alignas(16) bf16 As[128*40];
    __shared__ alignas(16) bf16 Bs[128*40];
    const int tid = threadIdx.x;
    const int m0 = blockIdx.x * 128, n0 = blockIdx.y * 128;
    const int wave = tid >> 6, lane = tid & 63;
    const int wm = (wave & 1) * 64, wn = (wave >> 1) * 64;
    const int lr = lane & 15, kg = lane >> 4;

    floatx4 acc[4][4] = {};

    const int lrow = tid >> 1;
    const int lcol = (tid & 1) * 16;
    const bf16* ap = A + (size_t)(m0 + lrow) * K + lcol;
    const bf16* bp = Wt + (size_t)(n0 + lrow) * K + lcol;
    bf16* as = As + lrow * 40 + lcol;
    bf16* bs = Bs + lrow * 40 + lcol;

    for (int k0 = 0; k0 < K; k0 += 32) {
        uint4 a0 = *(const uint4*)ap;
        uint4 a1 = *(const uint4*)(ap + 8);
        uint4 b0 = *(const uint4*)bp;
        uint4 b1 = *(const uint4*)(bp + 8);
        __syncthreads();
        *(uint4*)as = a0; *(uint4*)(as + 8) = a1;
        *(uint4*)bs = b0; *(uint4*)(bs + 8) = b1;
        __syncthreads();
        ap += 32; bp += 32;
        bf16x8 af[4], bfr[4];
        #pragma unroll
        for (int i = 0; i < 4; i++) {
            af[i]  = *(const bf16x8*)(As + (wm + i*16 + lr) * 40 + kg * 8);
            bfr[i] = *(const bf16x8*)(Bs + (wn + i*16 + lr) * 40 + kg * 8);
        }
        #pragma unroll
        for (int mi = 0; mi < 4; mi++)
            #pragma unroll
            for (int ni = 0; ni < 4; ni++)
                acc[mi][ni] = __builtin_amdgcn_mfma_f32_16x16x32_bf16(af[mi], bfr[ni], acc[mi][ni], 0, 0, 0);
    }

    #pragma unroll
    for (int ni = 0; ni < 4; ni++) {
        int col = n0 + wn + ni*16 + lr;
        float bv = bias[col];
        #pragma unroll
        for (int mi = 0; mi < 4; mi++) {
            int rowb = m0 + wm + mi*16 + kg*4;
            #pragma unroll
            for (int r = 0; r < 4; r++) {
                float v = acc[mi][ni][r] + bv;
                C[(size_t)(rowb + r) * N + col] = (bf16)v;
            }
        }
    }
}

// ---------------- small-K cross attention, in-place on Q rows ----------------
// one 64-lane wave per row; 8 lanes per head (8 dims each)
__global__ __launch_bounds__(256) void attn_apply(bf16* __restrict__ Q,
                                                  const bf16* __restrict__ Kp,
                                                  const bf16* __restrict__ Vp,
                                                  const int* __restrict__ mask, int Kk)
{
    __shared__ alignas(16) bf16 ks[NC_K*512];
    __shared__ alignas(16) bf16 vs[NC_K*512];
    __shared__ float cb[32];
    const int tid = threadIdx.x;
    const int b = blockIdx.x >> 4;
    const int chunk = blockIdx.x & 15;
    int nv = Kk * 512 / 8;
    for (int i = tid; i < nv; i += 256) {
        ((uint4*)ks)[i] = ((const uint4*)Kp)[i];
        ((uint4*)vs)[i] = ((const uint4*)Vp)[i];
    }
    if (tid < Kk) cb[tid] = (float)mask[b*Kk + tid];
    __syncthreads();
    const int wave = tid >> 6, lane = tid & 63;
    const int j = lane & 7;
    const int grpbase = lane & ~7;
    for (int r = wave; r < 128; r += 4) {
        size_t row = ((size_t)b * S_LEN + chunk*128 + r) * 512;
        bf16x8 qv = *(const bf16x8*)(Q + row + lane*8);
        float qf[8];
        #pragma unroll
        for (int i = 0; i < 8; i++) qf[i] = (float)qv[i];
        float lk[3] = {-1e30f, -1e30f, -1e30f};
        for (int k = 0; k < Kk; k++) {
            bf16x8 kv = *(const bf16x8*)(ks + k*512 + lane*8);
            float p = 0.f;
            #pragma unroll
            for (int i = 0; i < 8; i++) p += qf[i] * (float)kv[i];
            p += __shfl_xor(p, 1);
            p += __shfl_xor(p, 2);
            p += __shfl_xor(p, 4);
            float lg = p * 0.125f + cb[k];
            if ((k & 7) == j) lk[k >> 3] = lg;
        }
        float m = fmaxf(lk[0], fmaxf(lk[1], lk[2]));
        m = fmaxf(m, __shfl_xor(m, 1));
        m = fmaxf(m, __shfl_xor(m, 2));
        m = fmaxf(m, __shfl_xor(m, 4));
        float e0 = expf(lk[0]-m), e1 = expf(lk[1]-m), e2 = expf(lk[2]-m);
        float sm = e0 + e1 + e2;
        sm += __shfl_xor(sm, 1); sm += __shfl_xor(sm, 2); sm += __shfl_xor(sm, 4);
        float inv = 1.f / sm;
        float av[3] = {e0*inv, e1*inv, e2*inv};
        float of[8] = {0,0,0,0,0,0,0,0};
        #pragma unroll
        for (int kb = 0; kb < 3; kb++) {
            float aval = av[kb];
            for (int jj = 0; jj < 8; jj++) {
                int k = kb*8 + jj;
                if (k >= Kk) break;
                float ak = __shfl(aval, grpbase | jj);
                bf16x8 vv = *(const bf16x8*)(vs + k*512 + lane*8);
                #pragma unroll
                for (int i = 0; i < 8; i++) of[i] += ak * (float)vv[i];
            }
        }
        bf16x8 ov;
        #pragma unroll
        for (int i = 0; i < 8; i++) ov[i] = (bf16)of[i];
        *(bf16x8*)(Q + row + lane*8) = ov;
    }
}

// ---------------- pooled attention weights: A[b,h,k] += sum_s softmax ----------------
__global__ __launch_bounds__(256) void attn_pool(const bf16* __restrict__ Q,
                                                 const bf16* __restrict__ Kp,
                                                 const int* __restrict__ mask,
                                                 float* __restrict__ Aout, int Kk)
{
    __shared__ alignas(16) bf16 ks[NC_K*512];
    __shared__ float cb[32];
    const int tid = threadIdx.x;
    const int b = blockIdx.x >> 4;
    const int chunk = blockIdx.x & 15;
    int nv = Kk * 512 / 8;
    for (int i = tid; i < nv; i += 256) ((uint4*)ks)[i] = ((const uint4*)Kp)[i];
    if (tid < Kk) cb[tid] = (float)mask[b*Kk + tid];
    __syncthreads();
    const int wave = tid >> 6, lane = tid & 63;
    const int j = lane & 7;
    float aacc[3] = {0.f, 0.f, 0.f};
    for (int r = wave; r < 128; r += 4) {
        size_t row = ((size_t)b * S_LEN + chunk*128 + r) * 512;
        bf16x8 qv = *(const bf16x8*)(Q + row + lane*8);
        float qf[8];
        #pragma unroll
        for (int i = 0; i < 8; i++) qf[i] = (float)qv[i];
        float lk[3] = {-1e30f, -1e30f, -1e30f};
        for (int k = 0; k < Kk; k++) {
            bf16x8 kv = *(const bf16x8*)(ks + k*512 + lane*8);
            float p = 0.f;
            #pragma unroll
            for (int i = 0; i < 8; i++) p += qf[i] * (float)kv[i];
            p += __shfl_xor(p, 1);
            p += __shfl_xor(p, 2);
            p += __shfl_xor(p, 4);
            float lg = p * 0.125f + cb[k];
            if ((k & 7) == j) lk[k >> 3] = lg;
        }
        float m = fmaxf(lk[0], fmaxf(lk[1], lk[2]));
        m = fmaxf(m, __shfl_xor(m, 1));
        m = fmaxf(m, __shfl_xor(m, 2));
        m = fmaxf(m, __shfl_xor(m, 4));
        float e0 = expf(lk[0]-m), e1 = expf(lk[1]-m), e2 = expf(lk[2]-m);
        float sm = e0 + e1 + e2;
        sm += __shfl_xor(sm, 1); sm += __shfl_xor(sm, 2); sm += __shfl_xor(sm, 4);
        float inv = 1.f / sm;
        aacc[0] += e0 * inv; aacc[1] += e1 * inv; aacc[2] += e2 * inv;
    }
    const int head = lane >> 3;
    #pragma unroll
    for (int kb = 0; kb < 3; kb++) {
        int k = kb*8 + j;
        if (k < Kk) atomicAdd(&Aout[(b*NHEAD + head)*Kk + k], aacc[kb]);
    }
}

// ---------------- finalize: out = ((A@v)@Wo + S*bo)/P ; pooled = c - m ----------------
__global__ __launch_bounds__(256) void finalize_kernel(const float* __restrict__ Ac,
                                                       const float* __restrict__ Am,
                                                       const float* __restrict__ vc32,
                                                       const float* __restrict__ vm32,
                                                       const float* __restrict__ cWo,
                                                       const float* __restrict__ mWo,
                                                       const float* __restrict__ cbo,
                                                       const float* __restrict__ mbo,
                                                       const float* __restrict__ P,
                                                       float* __restrict__ out)
{
    __shared__ float oc[512];
    __shared__ float om[512];
    int b = blockIdx.x, tid = threadIdx.x;
    for (int d = tid; d < 512; d += 256) {
        int h = d >> 6;
        float sc = 0.f;
        for (int k = 0; k < NC_K; k++) sc += Ac[(b*NHEAD + h)*NC_K + k] * vc32[k*512 + d];
        oc[d] = sc;
        float sm = 0.f;
        for (int k = 0; k < NM_K; k++) sm += Am[(b*NHEAD + h)*NM_K + k] * vm32[k*512 + d];
        om[d] = sm;
    }
    __syncthreads();
    float invP = 1.f / P[b];
    for (int j = tid; j < 512; j += 256) {
        float ac = 0.f, am = 0.f;
        for (int d = 0; d < 512; d++) {
            ac += oc[d] * cWo[d*512 + j];
            am += om[d] * mWo[d*512 + j];
        }
        float pc = (ac + 2048.f * cbo[j]) * invP;
        float pm = (am + 2048.f * mbo[j]) * invP;
        out[b*512 + j] = pc;
        out[BATCH*512 + b*512 + j] = pc - pm;
    }
}

extern "C" void kernel_launch(void* const* d_in, const int* in_sizes, int n_in,
                              void* d_out, int out_size, void* d_ws, size_t ws_size,
                              hipStream_t stream)
{
    (void)in_sizes; (void)n_in; (void)out_size;
    const float* emb   = (const float*)d_in[0];
    const int* emask   = (const int*)d_in[1];
    const int* pmask   = (const int*)d_in[2];
    /* d_in[3] frame_mask: cancels in softmax, unused */
    const int* cmask   = (const int*)d_in[4];
    const int* mmask   = (const int*)d_in[5];
    const float* W_lin = (const float*)d_in[6];
    const float* b_lin = (const float*)d_in[7];
    const float* ctab  = (const float*)d_in[8];
    const float* mtab  = (const float*)d_in[9];
    const float* cWq = (const float*)d_in[10]; const float* cbq = (const float*)d_in[11];
    const float* cWk = (const float*)d_in[12]; const float* cbk = (const float*)d_in[13];
    const float* cWv = (const float*)d_in[14]; const float* cbv = (const float*)d_in[15];
    const float* cWo = (const float*)d_in[16]; const float* cbo = (const float*)d_in[17];
    const float* mWq = (const float*)d_in[18]; const float* mbq = (const float*)d_in[19];
    const float* mWk = (const float*)d_in[20]; const float* mbk = (const float*)d_in[21];
    const float* mWv = (const float*)d_in[22]; const float* mbv = (const float*)d_in[23];
    const float* mWo = (const float*)d_in[24]; const float* mbo = (const float*)d_in[25];
    float* outp = (float*)d_out;

    if (ws_size < 271800000UL) return;  // need ~272 MB scratch

    char* ws = (char*)d_ws;
    bf16* ebf  = (bf16*)(ws + 0);           // 128 MB, aliases bufA+bufB (dead after gemm1)
    bf16* bufA = (bf16*)(ws + 0);           // 64 MB  q1c -> o1c (in-place)
    bf16* bufB = (bf16*)(ws + 67108864);    // 64 MB  q1m -> o1m
    bf16* bufX = (bf16*)(ws + 134217728);   // 64 MB  x
    bf16* bufC = (bf16*)(ws + 201326592);   // 64 MB  q2c then q2m
    size_t o = 268435456;
    bf16* WlinT = (bf16*)(ws + o); o += 1048576;
    bf16* WqTc  = (bf16*)(ws + o); o += 524288;
    bf16* WqTm  = (bf16*)(ws + o); o += 524288;
    bf16* WoqTc = (bf16*)(ws + o); o += 524288;
    bf16* WoqTm = (bf16*)(ws + o); o += 524288;
    bf16* kcb   = (bf16*)(ws + o); o += 19456;
    bf16* vcb   = (bf16*)(ws + o); o += 19456;
    bf16* kmb   = (bf16*)(ws + o); o += 10240;
    bf16* vmb   = (bf16*)(ws + o); o += 10240;
    float* vc32 = (float*)(ws + o); o += 38912;
    float* vm32 = (float*)(ws + o); o += 20480;
    float* bq2c = (float*)(ws + o); o += 2048;
    float* bq2m = (float*)(ws + o); o += 2048;
    float* P    = (float*)(ws + o); o += 128;
    float* Ac   = (float*)(ws + o); o += 19456;
    float* Am   = (float*)(ws + o); o += 10240;

    dim3 blk(256);

    // precompute / prep
    cvt_bf16_kernel<<<dim3(32768), blk, 0, stream>>>(emb, ebf, (long)65536 * 1024);
    init_small<<<dim3(32), blk, 0, stream>>>(emask, pmask, P, Ac, Am);
    transpose_to_bf16<<<dim3(16, 32), blk, 0, stream>>>(W_lin, WlinT, 1024, 512);
    transpose_to_bf16<<<dim3(16, 16), blk, 0, stream>>>(cWq, WqTc, 512, 512);
    transpose_to_bf16<<<dim3(16, 16), blk, 0, stream>>>(mWq, WqTm, 512, 512);
    kv_proj<<<dim3(NC_K), blk, 0, stream>>>(ctab, cWk, cbk, cWv, cbv, kcb, vcb, vc32);
    kv_proj<<<dim3(NM_K), blk, 0, stream>>>(mtab, mWk, mbk, mWv, mbv, kmb, vmb, vm32);
    fold_wq<<<dim3(512), blk, 0, stream>>>(cWo, cWq, WoqTc);
    fold_wq<<<dim3(512), blk, 0, stream>>>(mWo, mWq, WoqTm);
    bias_fold<<<dim3(1), blk, 0, stream>>>(cbo, cWq, cbq, bq2c);
    bias_fold<<<dim3(1), blk, 0, stream>>>(mbo, mWq, mbq, bq2m);

    // x = emb @ W_lin + b_lin
    gemm_bf16<<<dim3(512, 4), blk, 0, stream>>>(ebf, WlinT, b_lin, bufX, 65536, 512, 1024);
    // q1 = x @ Wq + bq (both branches)   [ebf dead -> bufA/bufB reuse its space]
    gemm_bf16<<<dim3(512, 4), blk, 0, stream>>>(bufX, WqTc, cbq, bufA, 65536, 512, 512);
    gemm_bf16<<<dim3(512, 4), blk, 0, stream>>>(bufX, WqTm, mbq, bufB, 65536, 512, 512);
    // o1 = attn(q1) in-place
    attn_apply<<<dim3(512), blk, 0, stream>>>(bufA, kcb, vcb, cmask, NC_K);
    attn_apply<<<dim3(512), blk, 0, stream>>>(bufB, kmb, vmb, mmask, NM_K);
    // q2 = o1 @ (Wo@Wq) + (bo@Wq + bq); pooled softmax weights
    gemm_bf16<<<dim3(512, 4), blk, 0, stream>>>(bufA, WoqTc, bq2c, bufC, 65536, 512, 512);
    attn_pool<<<dim3(512), blk, 0, stream>>>(bufC, kcb, cmask, Ac, NC_K);
    gemm_bf16<<<dim3(512, 4), blk, 0, stream>>>(bufB, WoqTm, bq2m, bufC, 65536, 512, 512);
    attn_pool<<<dim3(512), blk, 0, stream>>>(bufC, kmb, mmask, Am, NM_K);
    // outputs
    finalize_kernel<<<dim3(32), blk, 0, stream>>>(Ac, Am, vc32, vm32, cWo, mWo, cbo, mbo, P, outp);
}

// Round 2
// 954.424 us; speedup vs baseline: 1.7523x; 1.7523x over previous
//
#include <hip/hip_runtime.h>
#include <math.h>

typedef __bf16 bf16;
typedef __bf16 bf16x8 __attribute__((ext_vector_type(8)));
typedef float floatx4 __attribute__((ext_vector_type(4)));

#define S_LEN 2048
#define BATCH 32
#define NHEAD 8
#define KC 19
#define KM 10
#define HKC 152   // 8*19
#define HKM 80    // 8*10
#define NTOT 232  // HKC + HKM
#define NPAD 256

// ---------------- misc init: P[b], A2 zero, mask-bias table mb[b][n] ----------------
__global__ __launch_bounds__(256) void init_misc(const int* __restrict__ em, const int* __restrict__ pmask,
                                                 const int* __restrict__ cmask, const int* __restrict__ mmask,
                                                 float* __restrict__ P, float* __restrict__ A2,
                                                 float* __restrict__ mb)
{
    __shared__ int red[256];
    int b = blockIdx.x, tid = threadIdx.x;
    int s = 0;
    for (int i = tid; i < S_LEN; i += 256) s += em[b*S_LEN+i] * pmask[b*S_LEN+i];
    red[tid] = s; __syncthreads();
    for (int o = 128; o; o >>= 1) { if (tid < o) red[tid] += red[tid+o]; __syncthreads(); }
    if (tid == 0) P[b] = (float)red[0];
    float v = 0.f;
    if (tid < HKC) v = (float)cmask[b*KC + (tid % KC)];
    else if (tid < NTOT) v = (float)mmask[b*KM + ((tid - HKC) % KM)];
    mb[b*NPAD + tid] = v;
    A2[b*NPAD + tid] = 0.f;
}

__global__ __launch_bounds__(256) void zero_bf16_k(bf16* p, int n)
{ int i = blockIdx.x*256 + threadIdx.x; if (i < n) p[i] = (bf16)0.f; }

// ---------------- k1/v1 = tab@Wk+bk, tab@Wv+bv (fp32) ----------------
__global__ __launch_bounds__(256) void kv_proj32(const float* __restrict__ T,
                                                 const float* __restrict__ Wk, const float* __restrict__ bk,
                                                 const float* __restrict__ Wv, const float* __restrict__ bv,
                                                 float* __restrict__ k1, float* __restrict__ v1)
{
    __shared__ float trow[512];
    int r = blockIdx.x, tid = threadIdx.x;
    for (int i = tid; i < 512; i += 256) trow[i] = T[r*512+i];
    __syncthreads();
    for (int j = tid; j < 512; j += 256) {
        float sk = bk[j], sv = bv[j];
        for (int d = 0; d < 512; d++) { float t = trow[d]; sk += t*Wk[d*512+j]; sv += t*Wv[d*512+j]; }
        k1[r*512+j] = sk; v1[r*512+j] = sv;
    }
}

// ---------------- M[D,n=(h,k)] = sum_d W[D,h*64+d] * k1[k,h*64+d]; both layouts ----------------
__global__ __launch_bounds__(256) void make_M(const float* __restrict__ W, const float* __restrict__ k1,
                                              float* __restrict__ M_D, float* __restrict__ M_T,
                                              int K, int HK)
{
    __shared__ float wrow[512];
    int D = blockIdx.x, tid = threadIdx.x;
    for (int i = tid; i < 512; i += 256) wrow[i] = W[D*512+i];
    __syncthreads();
    for (int n = tid; n < HK; n += 256) {
        int h = n / K, k = n % K;
        const float* kr = k1 + k*512 + h*64;
        const float* wr = wrow + h*64;
        float s = 0.f;
        #pragma unroll 16
        for (int d = 0; d < 64; d++) s += wr[d]*kr[d];
        if (M_D) M_D[D*HK + n] = s;
        if (M_T) M_T[n*512 + D] = s;
    }
}

// ---------------- Bt[off+n, Din] = bf16(0.125 * sum_D W_lin[Din,D]*MqT[n,D]) ----------------
__global__ __launch_bounds__(256) void make_Mbig(const float* __restrict__ W_lin, const float* __restrict__ MqT,
                                                 bf16* __restrict__ Bt, int HK, int off)
{
    __shared__ float wrow[512];
    int Din = blockIdx.x, tid = threadIdx.x;
    for (int i = tid; i < 512; i += 256) wrow[i] = W_lin[Din*512+i];
    __syncthreads();
    for (int n = tid; n < HK; n += 256) {
        const float* mr = MqT + n*512;
        float s = 0.f;
        #pragma unroll 8
        for (int d = 0; d < 512; d++) s += wrow[d]*mr[d];
        Bt[(size_t)(off+n)*1024 + Din] = (bf16)(0.125f*s);
    }
}

// ---------------- out[off+n] = 0.125*( sum_D vecA[D]*MT[n,D]  +  sum_d vecB[h64+d]*k1[k,h64+d] ) ----------------
__global__ __launch_bounds__(256) void make_c(const float* __restrict__ vecA, const float* __restrict__ MT,
                                              const float* __restrict__ vecB, const float* __restrict__ k1,
                                              float* __restrict__ out, int K, int HK, int off)
{
    int n = threadIdx.x;
    if (n >= HK) return;
    int h = n / K, k = n % K;
    float s = 0.f;
    if (vecA) { const float* mr = MT + n*512; for (int D = 0; D < 512; D++) s += vecA[D]*mr[D]; }
    const float* kr = k1 + k*512 + h*64;
    const float* vb = vecB + h*64;
    for (int d = 0; d < 64; d++) s += vb[d]*kr[d];
    out[off+n] = 0.125f*s;
}

// ---------------- Woq = Wo@Wq (fp32) ----------------
__global__ __launch_bounds__(256) void make_woq(const float* __restrict__ Wo, const float* __restrict__ Wq,
                                                float* __restrict__ Woq)
{
    __shared__ float worow[512];
    int D = blockIdx.x, tid = threadIdx.x;
    for (int i = tid; i < 512; i += 256) worow[i] = Wo[D*512+i];
    __syncthreads();
    for (int j = tid; j < 512; j += 256) {
        float s = 0.f;
        for (int t = 0; t < 512; t++) s += worow[t]*Wq[t*512+j];
        Woq[D*512+j] = s;
    }
}

// ---------------- bq2 = bo@Wq + bq ----------------
__global__ __launch_bounds__(256) void make_bq2(const float* __restrict__ bo, const float* __restrict__ Wq,
                                                const float* __restrict__ bq, float* __restrict__ bq2)
{
    int tid = threadIdx.x;
    for (int j = tid; j < 512; j += 256) {
        float s = bq[j];
        for (int t = 0; t < 512; t++) s += bo[t]*Wq[t*512+j];
        bq2[j] = s;
    }
}

// ---------------- GT[off+n', off+n] = bf16(0.125 * sum_d v1[k(n),h(n)*64+d]*MwqD[h*64+d, n']) ----------------
__global__ __launch_bounds__(256) void make_GT(const float* __restrict__ v1, const float* __restrict__ MwqD,
                                               bf16* __restrict__ GT, int K, int HK, int off)
{
    __shared__ float vrow[64];
    int n = blockIdx.x, tid = threadIdx.x;
    int h = n / K, k = n % K;
    if (tid < 64) vrow[tid] = v1[k*512 + h*64 + tid];
    __syncthreads();
    for (int np = tid; np < HK; np += 256) {
        float s = 0.f;
        #pragma unroll 16
        for (int d = 0; d < 64; d++) s += vrow[d] * MwqD[(h*64+d)*HK + np];
        GT[(size_t)(off+np)*NPAD + off + n] = (bf16)(0.125f*s);
    }
}

// ---------------- W2[off+n, j] = sum_d v1[k,h64+d]*Wo[h64+d, j] ----------------
__global__ __launch_bounds__(256) void make_W2(const float* __restrict__ v1, const float* __restrict__ Wo,
                                               float* __restrict__ W2, int K, int off)
{
    __shared__ float vrow[64];
    int n = blockIdx.x, tid = threadIdx.x;
    int h = n / K, k = n % K;
    if (tid < 64) vrow[tid] = v1[k*512 + h*64 + tid];
    __syncthreads();
    for (int j = tid; j < 512; j += 256) {
        float s = 0.f;
        #pragma unroll 16
        for (int d = 0; d < 64; d++) s += vrow[d]*Wo[(h*64+d)*512 + j];
        W2[(size_t)(off+n)*512 + j] = s;
    }
}

// ================= G1: logits1 = emb @ Bt^T + bias ; softmax per head -> av1 (bf16) =================
// 128 rows x 256 cols per block; grid 512; 4 waves each all-rows x 64 cols.
__global__ __launch_bounds__(256, 2) void g1_kernel(const float* __restrict__ emb,
                                                    const bf16* __restrict__ Bt,
                                                    const float* __restrict__ c1,
                                                    const float* __restrict__ mb,
                                                    bf16* __restrict__ av1)
{
    __shared__ union UU {
        struct { bf16 As[128*40]; bf16 Bs[256*40]; } s;
        bf16 Ls[128*264];
    } u;
    __shared__ float bias[256];
    const int tid = threadIdx.x;
    const int m0 = blockIdx.x*128, b = blockIdx.x >> 4;
    bias[tid] = c1[tid] + mb[b*NPAD + tid];
    const int wave = tid >> 6, lane = tid & 63, lr = lane & 15, kg = lane >> 4;
    floatx4 acc[8][4] = {};
    const int arow = tid >> 1, acol = (tid & 1)*16;
    const float* ap = emb + (size_t)(m0 + arow)*1024 + acol;
    bf16* asw = u.s.As + arow*40 + acol;
    const bf16* bp = Bt + (size_t)tid*1024;
    bf16* bsw = u.s.Bs + tid*40;
    const bf16* afp = u.s.As + lr*40 + kg*8;
    const bf16* bfp = u.s.Bs + (wave*64 + lr)*40 + kg*8;

    for (int k0 = 0; k0 < 1024; k0 += 32) {
        float4 f0 = *(const float4*)(ap + k0);
        float4 f1 = *(const float4*)(ap + k0 + 4);
        float4 f2 = *(const float4*)(ap + k0 + 8);
        float4 f3 = *(const float4*)(ap + k0 + 12);
        uint4 b0 = *(const uint4*)(bp + k0);
        uint4 b1 = *(const uint4*)(bp + k0 + 8);
        uint4 b2 = *(const uint4*)(bp + k0 + 16);
        uint4 b3 = *(const uint4*)(bp + k0 + 24);
        __syncthreads();
        bf16x8 p0, p1;
        p0[0]=(bf16)f0.x; p0[1]=(bf16)f0.y; p0[2]=(bf16)f0.z; p0[3]=(bf16)f0.w;
        p0[4]=(bf16)f1.x; p0[5]=(bf16)f1.y; p0[6]=(bf16)f1.z; p0[7]=(bf16)f1.w;
        p1[0]=(bf16)f2.x; p1[1]=(bf16)f2.y; p1[2]=(bf16)f2.z; p1[3]=(bf16)f2.w;
        p1[4]=(bf16)f3.x; p1[5]=(bf16)f3.y; p1[6]=(bf16)f3.z; p1[7]=(bf16)f3.w;
        *(bf16x8*)asw = p0; *(bf16x8*)(asw + 8) = p1;
        *(uint4*)bsw = b0; *(uint4*)(bsw + 8) = b1; *(uint4*)(bsw + 16) = b2; *(uint4*)(bsw + 24) = b3;
        __syncthreads();
        bf16x8 af[8], bfr[4];
        #pragma unroll
        for (int mi = 0; mi < 8; mi++) af[mi] = *(const bf16x8*)(afp + mi*16*40);
        #pragma unroll
        for (int nt = 0; nt < 4; nt++) bfr[nt] = *(const bf16x8*)(bfp + nt*16*40);
        #pragma unroll
        for (int mi = 0; mi < 8; mi++)
            #pragma unroll
            for (int nt = 0; nt < 4; nt++)
                acc[mi][nt] = __builtin_amdgcn_mfma_f32_16x16x32_bf16(af[mi], bfr[nt], acc[mi][nt], 0, 0, 0);
    }
    __syncthreads();
    // logits -> Ls (bf16)
    #pragma unroll
    for (int nt = 0; nt < 4; nt++) {
        int col = wave*64 + nt*16 + lr;
        float bb = bias[col];
        #pragma unroll
        for (int mi = 0; mi < 8; mi++) {
            int row = mi*16 + kg*4;
            #pragma unroll
            for (int r = 0; r < 4; r++)
                u.Ls[(row + r)*264 + col] = (bf16)(acc[mi][nt][r] + bb);
        }
    }
    __syncthreads();
    // softmax per head: threads 0..127 cultural (rows), 128..255 moral
    {
        int row = tid & 127;
        bf16* Lr = u.Ls + row*264;
        if (tid < 128) {
            for (int h = 0; h < NHEAD; h++) {
                float lv[KC]; float m = -1e30f;
                #pragma unroll
                for (int j = 0; j < KC; j++) { lv[j] = (float)Lr[h*KC + j]; m = fmaxf(m, lv[j]); }
                float s = 0.f;
                #pragma unroll
                for (int j = 0; j < KC; j++) { lv[j] = __expf(lv[j] - m); s += lv[j]; }
                float inv = 1.f / s;
                #pragma unroll
                for (int j = 0; j < KC; j++) Lr[h*KC + j] = (bf16)(lv[j]*inv);
            }
        } else {
            for (int h = 0; h < NHEAD; h++) {
                float lv[KM]; float m = -1e30f;
                #pragma unroll
                for (int j = 0; j < KM; j++) { lv[j] = (float)Lr[HKC + h*KM + j]; m = fmaxf(m, lv[j]); }
                float s = 0.f;
                #pragma unroll
                for (int j = 0; j < KM; j++) { lv[j] = __expf(lv[j] - m); s += lv[j]; }
                float inv = 1.f / s;
                #pragma unroll
                for (int j = 0; j < KM; j++) Lr[HKC + h*KM + j] = (bf16)(lv[j]*inv);
            }
            for (int c = NTOT; c < NPAD; c++) Lr[c] = (bf16)0.f;
        }
    }
    __syncthreads();
    // store av1 tile
    for (int c = tid; c < 4096; c += 256) {
        int row = c >> 5, c8 = (c & 31)*8;
        *(uint4*)(av1 + (size_t)(m0 + row)*NPAD + c8) = *(const uint4*)(u.Ls + row*264 + c8);
    }
}

// ================= G2: logits2 = av1 @ GT^T + bias ; softmax ; pool -> A2 atomics =================
__global__ __launch_bounds__(256, 2) void g2_kernel(const bf16* __restrict__ av1,
                                                    const bf16* __restrict__ GT,
                                                    const float* __restrict__ c2,
                                                    const float* __restrict__ mb,
                                                    float* __restrict__ A2)
{
    __shared__ union UU {
        struct { bf16 As[128*40]; bf16 Bs[256*40]; } s;
        bf16 Ls[128*264];
    } u;
    __shared__ float bias[256];
    const int tid = threadIdx.x;
    const int m0 = blockIdx.x*128, b = blockIdx.x >> 4;
    bias[tid] = c2[tid] + mb[b*NPAD + tid];
    const int wave = tid >> 6, lane = tid & 63, lr = lane & 15, kg = lane >> 4;
    floatx4 acc[8][4] = {};
    const int arow = tid >> 1, acol = (tid & 1)*16;
    const bf16* ap = av1 + (size_t)(m0 + arow)*NPAD + acol;
    bf16* asw = u.s.As + arow*40 + acol;
    const bf16* bp = GT + (size_t)tid*NPAD;
    bf16* bsw = u.s.Bs + tid*40;
    const bf16* afp = u.s.As + lr*40 + kg*8;
    const bf16* bfp = u.s.Bs + (wave*64 + lr)*40 + kg*8;

    for (int k0 = 0; k0 < 256; k0 += 32) {
        uint4 a0 = *(const uint4*)(ap + k0);
        uint4 a1 = *(const uint4*)(ap + k0 + 8);
        uint4 b0 = *(const uint4*)(bp + k0);
        uint4 b1 = *(const uint4*)(bp + k0 + 8);
        uint4 b2 = *(const uint4*)(bp + k0 + 16);
        uint4 b3 = *(const uint4*)(bp + k0 + 24);
        __syncthreads();
        *(uint4*)asw = a0; *(uint4*)(asw + 8) = a1;
        *(uint4*)bsw = b0; *(uint4*)(bsw + 8) = b1; *(uint4*)(bsw + 16) = b2; *(uint4*)(bsw + 24) = b3;
        __syncthreads();
        bf16x8 af[8], bfr[4];
        #pragma unroll
        for (int mi = 0; mi < 8; mi++) af[mi] = *(const bf16x8*)(afp + mi*16*40);
        #pragma unroll
        for (int nt = 0; nt < 4; nt++) bfr[nt] = *(const bf16x8*)(bfp + nt*16*40);
        #pragma unroll
        for (int mi = 0; mi < 8; mi++)
            #pragma unroll
            for (int nt = 0; nt < 4; nt++)
                acc[mi][nt] = __builtin_amdgcn_mfma_f32_16x16x32_bf16(af[mi], bfr[nt], acc[mi][nt], 0, 0, 0);
    }
    __syncthreads();
    #pragma unroll
    for (int nt = 0; nt < 4; nt++) {
        int col = wave*64 + nt*16 + lr;
        float bb = bias[col];
        #pragma unroll
        for (int mi = 0; mi < 8; mi++) {
            int row = mi*16 + kg*4;
            #pragma unroll
            for (int r = 0; r < 4; r++)
                u.Ls[(row + r)*264 + col] = (bf16)(acc[mi][nt][r] + bb);
        }
    }
    __syncthreads();
    {
        int row = tid & 127;
        bf16* Lr = u.Ls + row*264;
        if (tid < 128) {
            for (int h = 0; h < NHEAD; h++) {
                float lv[KC]; float m = -1e30f;
                #pragma unroll
                for (int j = 0; j < KC; j++) { lv[j] = (float)Lr[h*KC + j]; m = fmaxf(m, lv[j]); }
                float s = 0.f;
                #pragma unroll
                for (int j = 0; j < KC; j++) { lv[j] = __expf(lv[j] - m); s += lv[j]; }
                float inv = 1.f / s;
                #pragma unroll
                for (int j = 0; j < KC; j++) Lr[h*KC + j] = (bf16)(lv[j]*inv);
            }
        } else {
            for (int h = 0; h < NHEAD; h++) {
                float lv[KM]; float m = -1e30f;
                #pragma unroll
                for (int j = 0; j < KM; j++) { lv[j] = (float)Lr[HKC + h*KM + j]; m = fmaxf(m, lv[j]); }
                float s = 0.f;
                #pragma unroll
                for (int j = 0; j < KM; j++) { lv[j] = __expf(lv[j] - m); s += lv[j]; }
                float inv = 1.f / s;
                #pragma unroll
                for (int j = 0; j < KM; j++) Lr[HKC + h*KM + j] = (bf16)(lv[j]*inv);
            }
        }
    }
    __syncthreads();
    // pool: col per thread, sum over 128 rows
    {
        float s = 0.f;
        for (int r = 0; r < 128; r++) s += (float)u.Ls[r*264 + tid];
        if (tid < NTOT) atomicAdd(&A2[b*NPAD + tid], s);
    }
}

// ---------------- finalize ----------------
__global__ __launch_bounds__(256) void finalize_kernel(const float* __restrict__ A2, const float* __restrict__ W2,
                                                       const float* __restrict__ cbo, const float* __restrict__ mbo,
                                                       const float* __restrict__ P, float* __restrict__ out)
{
    __shared__ float a[NTOT];
    int b = blockIdx.x, tid = threadIdx.x;
    if (tid < NTOT) a[tid] = A2[b*NPAD + tid];
    __syncthreads();
    float invP = 1.f / P[b];
    for (int j = tid; j < 512; j += 256) {
        float pc = 2048.f*cbo[j], pm = 2048.f*mbo[j];
        for (int n = 0; n < HKC; n++) pc += a[n]*W2[n*512 + j];
        for (int n = HKC; n < NTOT; n++) pm += a[n]*W2[n*512 + j];
        out[b*512 + j] = pc*invP;
        out[BATCH*512 + b*512 + j] = (pc - pm)*invP;
    }
}

extern "C" void kernel_launch(void* const* d_in, const int* in_sizes, int n_in,
                              void* d_out, int out_size, void* d_ws, size_t ws_size,
                              hipStream_t stream)
{
    (void)in_sizes; (void)n_in; (void)out_size;
    const float* emb   = (const float*)d_in[0];
    const int* emask   = (const int*)d_in[1];
    const int* pmask   = (const int*)d_in[2];
    /* d_in[3] frame_mask: cancels in softmax */
    const int* cmask   = (const int*)d_in[4];
    const int* mmask   = (const int*)d_in[5];
    const float* W_lin = (const float*)d_in[6];
    const float* b_lin = (const float*)d_in[7];
    const float* ctab  = (const float*)d_in[8];
    const float* mtab  = (const float*)d_in[9];
    const float* cWq = (const float*)d_in[10]; const float* cbq = (const float*)d_in[11];
    const float* cWk = (const float*)d_in[12]; const float* cbk = (const float*)d_in[13];
    const float* cWv = (const float*)d_in[14]; const float* cbv = (const float*)d_in[15];
    const float* cWo = (const float*)d_in[16]; const float* cbo = (const float*)d_in[17];
    const float* mWq = (const float*)d_in[18]; const float* mbq = (const float*)d_in[19];
    const float* mWk = (const float*)d_in[20]; const float* mbk = (const float*)d_in[21];
    const float* mWv = (const float*)d_in[22]; const float* mbv = (const float*)d_in[23];
    const float* mWo = (const float*)d_in[24]; const float* mbo = (const float*)d_in[25];
    float* outp = (float*)d_out;

    if (ws_size < 64000000UL) return;

    char* ws = (char*)d_ws;
    size_t o = 0;
    bf16* av1   = (bf16*)(ws + o); o += (size_t)65536*NPAD*2;   // 33.5 MB
    bf16* Bt    = (bf16*)(ws + o); o += 256*1024*2;
    bf16* GT    = (bf16*)(ws + o); o += NPAD*NPAD*2;
    float* k1c  = (float*)(ws + o); o += KC*512*4;
    float* v1c  = (float*)(ws + o); o += KC*512*4;
    float* k1m  = (float*)(ws + o); o += KM*512*4;
    float* v1m  = (float*)(ws + o); o += KM*512*4;
    float* MqTc = (float*)(ws + o); o += (size_t)HKC*512*4;
    float* MqTm = (float*)(ws + o); o += (size_t)HKM*512*4;
    float* MwqDc= (float*)(ws + o); o += (size_t)512*HKC*4;
    float* MwqDm= (float*)(ws + o); o += (size_t)512*HKM*4;
    float* Woqc = (float*)(ws + o); o += (size_t)512*512*4;
    float* Woqm = (float*)(ws + o); o += (size_t)512*512*4;
    float* W2   = (float*)(ws + o); o += (size_t)NTOT*512*4;
    float* c1   = (float*)(ws + o); o += NPAD*4;
    float* c2   = (float*)(ws + o); o += NPAD*4;
    float* bq2c = (float*)(ws + o); o += 512*4;
    float* bq2m = (float*)(ws + o); o += 512*4;
    float* mbt  = (float*)(ws + o); o += BATCH*NPAD*4;
    float* P    = (float*)(ws + o); o += 128;
    float* A2   = (float*)(ws + o); o += BATCH*NPAD*4;

    dim3 blk(256);

    init_misc<<<dim3(BATCH), blk, 0, stream>>>(emask, pmask, cmask, mmask, P, A2, mbt);
    zero_bf16_k<<<dim3(256), blk, 0, stream>>>(GT, NPAD*NPAD);
    zero_bf16_k<<<dim3(96), blk, 0, stream>>>(Bt + (size_t)NTOT*1024, (NPAD - NTOT)*1024);
    zero_bf16_k<<<dim3(1), blk, 0, stream>>>((bf16*)c1, 2*NPAD*2);  // zero c1+c2 (contiguous fp32 as bf16 pairs)

    kv_proj32<<<dim3(KC), blk, 0, stream>>>(ctab, cWk, cbk, cWv, cbv, k1c, v1c);
    kv_proj32<<<dim3(KM), blk, 0, stream>>>(mtab, mWk, mbk, mWv, mbv, k1m, v1m);

    make_M<<<dim3(512), blk, 0, stream>>>(cWq, k1c, (float*)nullptr, MqTc, KC, HKC);
    make_M<<<dim3(512), blk, 0, stream>>>(mWq, k1m, (float*)nullptr, MqTm, KM, HKM);
    make_Mbig<<<dim3(1024), blk, 0, stream>>>(W_lin, MqTc, Bt, HKC, 0);
    make_Mbig<<<dim3(1024), blk, 0, stream>>>(W_lin, MqTm, Bt, HKM, HKC);
    make_c<<<dim3(1), blk, 0, stream>>>(b_lin, MqTc, cbq, k1c, c1, KC, HKC, 0);
    make_c<<<dim3(1), blk, 0, stream>>>(b_lin, MqTm, mbq, k1m, c1, KM, HKM, HKC);

    make_woq<<<dim3(512), blk, 0, stream>>>(cWo, cWq, Woqc);
    make_woq<<<dim3(512), blk, 0, stream>>>(mWo, mWq, Woqm);
    make_bq2<<<dim3(1), blk, 0, stream>>>(cbo, cWq, cbq, bq2c);
    make_bq2<<<dim3(1), blk, 0, stream>>>(mbo, mWq, mbq, bq2m);
    make_M<<<dim3(512), blk, 0, stream>>>(Woqc, k1c, MwqDc, (float*)nullptr, KC, HKC);
    make_M<<<dim3(512), blk, 0, stream>>>(Woqm, k1m, MwqDm, (float*)nullptr, KM, HKM);
    make_c<<<dim3(1), blk, 0, stream>>>((const float*)nullptr, (const float*)nullptr, bq2c, k1c, c2, KC, HKC, 0);
    make_c<<<dim3(1), blk, 0, stream>>>((const float*)nullptr, (const float*)nullptr, bq2m, k1m, c2, KM, HKM, HKC);
    make_GT<<<dim3(HKC), blk, 0, stream>>>(v1c, MwqDc, GT, KC, HKC, 0);
    make_GT<<<dim3(HKM), blk, 0, stream>>>(v1m, MwqDm, GT, KM, HKM, HKC);
    make_W2<<<dim3(HKC), blk, 0, stream>>>(v1c, cWo, W2, KC, 0);
    make_W2<<<dim3(HKM), blk, 0, stream>>>(v1m, mWo, W2, KM, HKC);

    g1_kernel<<<dim3(512), blk, 0, stream>>>(emb, Bt, c1, mbt, av1);
    g2_kernel<<<dim3(512), blk, 0, stream>>>(av1, GT, c2, mbt, A2);
    finalize_kernel<<<dim3(BATCH), blk, 0, stream>>>(A2, W2, cbo, mbo, P, outp);
}